// Round 8
// baseline (205.007 us; speedup 1.0000x reference)
//
#include <hip/hip_runtime.h>
#include <stdint.h>

typedef __attribute__((ext_vector_type(8))) short bf16x8;
typedef __attribute__((ext_vector_type(4))) float f32x4;
typedef __attribute__((ext_vector_type(4))) unsigned short u16x4;
typedef unsigned short u16;

#define NBATCH 4
#define SEQ    4096
#define CIN    512
#define HD     64
#define OC     576      // f32 elements per out row
#define NROW   (NBATCH * SEQ)

__device__ __forceinline__ float b2f(u16 u) {
    union { uint32_t i; float f; } w; w.i = ((uint32_t)u) << 16; return w.f;
}
__device__ __forceinline__ u16 f2b(float f) {
    union { float f; uint32_t i; } w; w.f = f;
    uint32_t r = w.i + 0x7fffu + ((w.i >> 16) & 1u);
    return (u16)(r >> 16);
}
// pack two f32 -> two bf16 (RTNE) in one VGPR: lo = a, hi = b
__device__ __forceinline__ uint32_t cvtpk_bf16(float a, float b) {
    uint32_t r;
    asm("v_cvt_pk_bf16_f32 %0, %1, %2" : "=v"(r) : "v"(a), "v"(b));
    return r;
}

// ---------------------------------------------------------------------------
// Kernel 1: transpose f32 weights into bf16 wt[192][512] (unchanged).
// ---------------------------------------------------------------------------
__global__ void prep_wt(const float* __restrict__ Wq, const float* __restrict__ Wk,
                        const float* __restrict__ Wv, u16* __restrict__ wt) {
    int row = blockIdx.x;            // 0..191
    int g = row >> 6, j = row & 63;
    const float* W = (g == 0) ? Wq : (g == 1) ? Wk : Wv;
    for (int k = threadIdx.x; k < CIN; k += blockDim.x)
        wt[row * CIN + k] = f2b(W[k * HD + j]);
}

// ---------------------------------------------------------------------------
// Kernel 2: QKV projection, R8: smaller blocks for MORE CO-RESIDENCY +
// SHORTER CHAINS. R7 (32-row block, 64 KB panel) improved 46 -> ~37 us but
// 64 KB LDS caps at 2 blocks/CU (2 waves/SIMD). Now: 16-row block, 32 KB
// panel -> 4 blocks/CU (4 waves/SIMD); 4 waves split the 12 nt-tiles
// 3-each (full K=512), so per c-iter a wave does 2 LDS A-reads + 3 wt
// loads + 3 MFMA (half the R7 chain). Staging via global_load_lds with
// pre-swizzled global source (granule g = p ^ (row&15)), linear LDS dest;
// x-copy reads the LDS panel. Q pre-scaled by 0.125*log2(e) (R3).
// ---------------------------------------------------------------------------
__global__ __launch_bounds__(256) void proj(
    const float* __restrict__ x, const u16* __restrict__ wt,
    const float* __restrict__ bq, const float* __restrict__ bk, const float* __restrict__ bv,
    u16* __restrict__ qb, u16* __restrict__ kbuf, u16* __restrict__ vtb,
    float* __restrict__ out)
{
    __shared__ __align__(16) float xs[16 * 512];   // 32 KiB x-panel (swizzled)

    int tid = threadIdx.x;
    int lane = tid & 63, w = tid >> 6;   // 4 waves
    int m = lane & 15, quad = lane >> 4;
    int r0 = blockIdx.x * 16;            // first global row of this block

    // ---- stage x: 8 rounds of global_load_lds, 16 B per lane per round.
    // Linear LDS granule G = k*256 + w*64 + lane; phys (row r, slot p):
    // r = G/128 (wave-uniform), p = G%128. Global source pre-swizzled:
    // logical granule g = p ^ (r & 15).
    {
        int rw = w >> 1;                  // wave-uniform row parity
        int pp = (w & 1) * 64 + lane;     // phys granule within row
#pragma unroll
        for (int k = 0; k < 8; k++) {
            int r = k * 2 + rw;
            int g = pp ^ (r & 15);
            const float* src = x + (size_t)(r0 + r) * CIN + g * 4;
            float* dst = xs + (size_t)(k * 256 + w * 64 + lane) * 4;
            __builtin_amdgcn_global_load_lds(
                (const __attribute__((address_space(1))) void*)src,
                (__attribute__((address_space(3))) void*)dst, 16, 0, 0);
        }
    }
    __syncthreads();   // drains vmcnt -> panel ready

    int ntb = w * 3;                      // this wave's 3 output tiles

    f32x4 acc[3];
#pragma unroll
    for (int i = 0; i < 3; i++) acc[i] = (f32x4){0.f, 0.f, 0.f, 0.f};

    const float* xrow = xs + (size_t)m * 512;   // LDS row (MFMA k-row = m)

#pragma unroll
    for (int c = 0; c < 16; c++) {
        int L0 = c * 8 + quad * 2;           // logical granule of this lane's 8 floats
        f32x4 va = *(const f32x4*)(xrow + (size_t)((L0 ^ m) * 4));
        f32x4 vb = *(const f32x4*)(xrow + (size_t)(((L0 + 1) ^ m) * 4));
        bf16x8 a;
#pragma unroll
        for (int j = 0; j < 4; j++) { a[j] = (short)f2b(va[j]); a[4 + j] = (short)f2b(vb[j]); }
#pragma unroll
        for (int t = 0; t < 3; t++) {
            int nt = ntb + t;
            bf16x8 b = *(const bf16x8*)(wt + (size_t)(nt * 16 + m) * CIN + c * 32 + quad * 8);
            acc[t] = __builtin_amdgcn_mfma_f32_16x16x32_bf16(a, b, acc[t], 0, 0, 0);
        }
    }

    // ---- x-copy from the LDS panel. Thread tid handles granule
    // G = k*256 + tid; phys (r,p) holds logical col (p ^ (r&15))*4.
#pragma unroll
    for (int k = 0; k < 8; k++) {
        int G = k * 256 + tid;
        int r = G >> 7, p = G & 127;
        f32x4 v = *(const f32x4*)(xs + (size_t)G * 4);
        int col = (p ^ (r & 15)) * 4;
        *(f32x4*)(out + (size_t)(r0 + r) * OC + col) = v;
    }

    int n  = r0 >> 12;          // batch
    int tl = r0 & (SEQ - 1);    // t within batch

    const float SCQ = 0.125f * 1.44269504088896f;   // scale * log2(e), baked into Q

#pragma unroll
    for (int t = 0; t < 3; t++) {
        int nt = ntb + t;                 // 0..11, wave-uniform
        int bi = (nt & 3) * 16 + m;       // column within its 64-wide matrix
        if (nt < 4) {
            float biasq = bq[bi];
#pragma unroll
            for (int reg = 0; reg < 4; reg++) {
                size_t r = (size_t)(r0 + quad * 4 + reg);
                qb[r * HD + bi] = f2b((acc[t][reg] + biasq) * SCQ);
            }
        } else if (nt < 8) {
            float biask = bk[bi];
#pragma unroll
            for (int reg = 0; reg < 4; reg++) {
                size_t r = (size_t)(r0 + quad * 4 + reg);
                kbuf[r * HD + bi] = f2b(acc[t][reg] + biask);
            }
        } else {
            float biasv = bv[bi];
            u16x4 pk;
#pragma unroll
            for (int reg = 0; reg < 4; reg++) pk[reg] = f2b(acc[t][reg] + biasv);
            u16* vp = vtb + (size_t)(n * HD + bi) * SEQ + tl + quad * 4;
            *(u16x4*)vp = pk;
        }
    }
}

// ---------------------------------------------------------------------------
// Kernel 3: causal flash attention, R8 LONG-LOOP MERGE-FREE restructure.
// Diagnosis: the 8-way key-split gave avg-4-iteration wave loops (many
// waves cnt 0/1) -> no pipelining steady state, full prologue latency per
// wave, then a merge barrier; attn pinned ~43 us (resource bound ~5 us).
// New structure: 4-wave blocks (256 thr); wave = (q-subtile qs, v-half vh)
// of a QBLK=32 tile. Each wave runs the FULL key loop (1..64 iters) and
// owns its 16q x 32v output -> NO merge, NO __syncthreads anywhere.
// QK + softmax duplicated across the 2 v-halves (MFMA 5%, VALU 23% ->
// headroom is the cheap currency). Grid 512 = 2 blocks/CU; index map puts
// tile jj and 127-jj on the same CU (sum-constant work, robust even with
// all blocks resident). Epilogue: 1/l scale in-register, per-wave LDS
// transpose (reuses the P buffer), coalesced f32x4 stores.
// Numerics unchanged: Q pre-scaled, l via ones-MFMA, defer-max THR=8,
// cvt_pk packing.
// ---------------------------------------------------------------------------
__global__ __launch_bounds__(256) void attn(
    const u16* __restrict__ qb, const u16* __restrict__ kbuf,
    const u16* __restrict__ vtb, float* __restrict__ out)
{
    __shared__ __align__(16) short plds[4][16 * 72];   // per-wave P / transpose buf

    int tid = threadIdx.x;
    int lane = tid & 63, w = tid >> 6;   // 4 waves
    int m = lane & 15, quad = lane >> 4;
    int qs = w >> 1, vh = w & 1;         // wave = (q-subtile, v-half)

    int idx = blockIdx.x;                 // 0..511
    int xcd = idx & 7;                    // HW round-robins blockIdx across XCDs
    int batch = xcd >> 1;                 // 2 XCDs per batch
    int par = xcd & 1;
    int li = idx >> 3;                    // 0..63 within this XCD
    // antithetic: first 32 li heavy (jj=127-..), last 32 light (jj asc);
    // blocks li and li+32 land on the same CU -> per-CU work ~constant.
    int jj = (li < 32) ? (127 - (li * 2 + par)) : ((li - 32) * 2 + par);
    int t0 = jj * 32;
    int nkb = (jj >> 1) + 1;              // 64-key blocks needed

    const u16* kp = kbuf + (size_t)(batch * SEQ + m) * HD + quad * 8;           // + s*HD
    const u16* vp = vtb + (size_t)(batch * HD + vh * 32 + m) * SEQ + quad * 8;  // + nt*16*SEQ + s
    const u16* qpb = qb + (size_t)(batch * SEQ + t0 + qs * 16 + m) * HD + quad * 8;

    bf16x8 ones;
#pragma unroll
    for (int i = 0; i < 8; i++) ones[i] = (short)0x3F80;   // bf16 1.0

    bf16x8 qf0 = *(const bf16x8*)(qpb);
    bf16x8 qf1 = *(const bf16x8*)(qpb + 32);

    float mst = -1e30f;
    f32x4 o0 = (f32x4){0.f, 0.f, 0.f, 0.f};
    f32x4 o1 = (f32x4){0.f, 0.f, 0.f, 0.f};
    f32x4 ol = (f32x4){0.f, 0.f, 0.f, 0.f};

    short* pw = &plds[w][0];

    // preload K A-frags for kb = 0
    bf16x8 k0[4], k1[4];
#pragma unroll
    for (int st = 0; st < 4; st++) {
        k0[st] = *(const bf16x8*)(kp + (size_t)(st * 16) * HD);
        k1[st] = *(const bf16x8*)(kp + (size_t)(st * 16) * HD + 32);
    }

    for (int kb = 0; kb < nkb; kb++) {
        int s0 = kb * 64;

        // V loads for this wave's v-half (issued early, consumed after softmax)
        bf16x8 vf0[2], vf1[2];
#pragma unroll
        for (int nt = 0; nt < 2; nt++) {
            vf0[nt] = *(const bf16x8*)(vp + (size_t)(nt * 16) * SEQ + s0);
            vf1[nt] = *(const bf16x8*)(vp + (size_t)(nt * 16) * SEQ + s0 + 32);
        }

        // S^T = K Q^T for this wave's q-subtile (scores pre-scaled via Q)
        f32x4 s[4];
#pragma unroll
        for (int st = 0; st < 4; st++) {
            f32x4 a = (f32x4){0.f, 0.f, 0.f, 0.f};
            a = __builtin_amdgcn_mfma_f32_16x16x32_bf16(k0[st], qf0, a, 0, 0, 0);
            a = __builtin_amdgcn_mfma_f32_16x16x32_bf16(k1[st], qf1, a, 0, 0, 0);
            s[st] = a;
        }

        // prefetch next key-block (long loop -> steady-state pipelining)
        if (kb + 1 < nkb) {
            int sn = s0 + 64;
#pragma unroll
            for (int st = 0; st < 4; st++) {
                k0[st] = *(const bf16x8*)(kp + (size_t)(sn + st * 16) * HD);
                k1[st] = *(const bf16x8*)(kp + (size_t)(sn + st * 16) * HD + 32);
            }
        }

        // causal mask only on the diagonal block (wave-uniform branch)
        if (kb == nkb - 1) {
#pragma unroll
            for (int st = 0; st < 4; st++)
#pragma unroll
                for (int r = 0; r < 4; r++) {
                    int key = s0 + st * 16 + quad * 4 + r;
                    if (key > t0 + qs * 16 + m) s[st][r] = -1e30f;
                }
        }

        // online softmax (per-query state: query = m)
        float mx = -1e30f;
#pragma unroll
        for (int st = 0; st < 4; st++) {
            float a01 = fmaxf(s[st][0], s[st][1]);
            float a23 = fmaxf(s[st][2], s[st][3]);
            mx = fmaxf(mx, fmaxf(a01, a23));
        }
        mx = fmaxf(mx, __shfl_xor(mx, 16, 64));
        mx = fmaxf(mx, __shfl_xor(mx, 32, 64));

        // defer-max: only rescale when max grew past threshold
        if (__any(mx > mst + 8.0f)) {
            float mn = fmaxf(mst, mx);
            float al = exp2f(mst - mn);
#pragma unroll
            for (int r = 0; r < 4; r++) { o0[r] *= al; o1[r] *= al; }
            ol[0] *= al;   // only reg 0 of ol is ever read
            mst = mn;
        }

        // P = 2^(s - m), pack bf16, stage P^T in this wave's LDS buffer
#pragma unroll
        for (int st = 0; st < 4; st++) {
            float e0 = exp2f(s[st][0] - mst);
            float e1 = exp2f(s[st][1] - mst);
            float e2 = exp2f(s[st][2] - mst);
            float e3 = exp2f(s[st][3] - mst);
            uint2 pk2;
            pk2.x = cvtpk_bf16(e0, e1);
            pk2.y = cvtpk_bf16(e2, e3);
            *(uint2*)(pw + m * 72 + st * 16 + quad * 4) = pk2;
        }
        __asm__ volatile("" ::: "memory");   // pack-writes before frag-reads
        bf16x8 pf0 = *(const bf16x8*)(pw + m * 72 + quad * 8);
        bf16x8 pf1 = *(const bf16x8*)(pw + m * 72 + 32 + quad * 8);
        __asm__ volatile("" ::: "memory");   // frag-reads before next pack

        // O^T += V^T P^T ; l += ones . P^T
        o0 = __builtin_amdgcn_mfma_f32_16x16x32_bf16(vf0[0], pf0, o0, 0, 0, 0);
        o0 = __builtin_amdgcn_mfma_f32_16x16x32_bf16(vf1[0], pf1, o0, 0, 0, 0);
        o1 = __builtin_amdgcn_mfma_f32_16x16x32_bf16(vf0[1], pf0, o1, 0, 0, 0);
        o1 = __builtin_amdgcn_mfma_f32_16x16x32_bf16(vf1[1], pf1, o1, 0, 0, 0);
        ol = __builtin_amdgcn_mfma_f32_16x16x32_bf16(ones, pf0, ol, 0, 0, 0);
        ol = __builtin_amdgcn_mfma_f32_16x16x32_bf16(ones, pf1, ol, 0, 0, 0);
    }

    // ---- epilogue: scale by 1/l, transpose via this wave's LDS buffer
    // (P buffer dead; 32x17 f32 = 2176 B <= 2304 B), coalesced stores.
    float inv = 1.0f / ol[0];
    float* tb = (float*)pw;               // [32][17] f32, padded
    __asm__ volatile("" ::: "memory");
#pragma unroll
    for (int r = 0; r < 4; r++) {
        tb[(0 * 16 + quad * 4 + r) * 17 + m] = o0[r] * inv;
        tb[(1 * 16 + quad * 4 + r) * 17 + m] = o1[r] * inv;
    }
    __asm__ volatile("" ::: "memory");
    {
        int q = lane >> 2, vg = lane & 3;       // q 0..15, v-group 0..3 (8 each)
        f32x4 ra, rb;
#pragma unroll
        for (int i = 0; i < 4; i++) {
            ra[i] = tb[(vg * 8 + i) * 17 + q];
            rb[i] = tb[(vg * 8 + 4 + i) * 17 + q];
        }
        float* op = out + (size_t)(batch * SEQ + t0 + qs * 16 + q) * OC + CIN + vh * 32 + vg * 8;
        *(f32x4*)op = ra;
        *(f32x4*)(op + 4) = rb;
    }
}

// ---------------------------------------------------------------------------
extern "C" void kernel_launch(void* const* d_in, const int* in_sizes, int n_in,
                              void* d_out, int out_size, void* d_ws, size_t ws_size,
                              hipStream_t stream) {
    const float* x  = (const float*)d_in[0];
    const float* Wq = (const float*)d_in[1];
    const float* bq = (const float*)d_in[2];
    const float* Wk = (const float*)d_in[3];
    const float* bk = (const float*)d_in[4];
    const float* Wv = (const float*)d_in[5];
    const float* bv = (const float*)d_in[6];
    float* out = (float*)d_out;

    u16* ws  = (u16*)d_ws;
    u16* wt  = ws;                          // 192*512 elems (pad to 128K)
    u16* qb  = ws + 131072;                 // 16384*64 = 1M elems
    u16* kb  = qb + 16384 * 64;
    u16* vtb = kb + 16384 * 64;             // transposed v: [4][64][4096]

    prep_wt<<<dim3(192), dim3(256), 0, stream>>>(Wq, Wk, Wv, wt);
    proj<<<dim3(1024), dim3(256), 0, stream>>>(x, wt, bq, bk, bv, qb, kb, vtb, out);
    attn<<<dim3(512), dim3(256), 0, stream>>>(qb, kb, vtb, out);
}

// Round 9
// 166.322 us; speedup vs baseline: 1.2326x; 1.2326x over previous
//
#include <hip/hip_runtime.h>
#include <stdint.h>

typedef __attribute__((ext_vector_type(8))) short bf16x8;
typedef __attribute__((ext_vector_type(4))) float f32x4;
typedef __attribute__((ext_vector_type(4))) unsigned short u16x4;
typedef unsigned short u16;

#define NBATCH 4
#define SEQ    4096
#define CIN    512
#define HD     64
#define OC     576      // f32 elements per out row
#define NROW   (NBATCH * SEQ)

__device__ __forceinline__ float b2f(u16 u) {
    union { uint32_t i; float f; } w; w.i = ((uint32_t)u) << 16; return w.f;
}
__device__ __forceinline__ u16 f2b(float f) {
    union { float f; uint32_t i; } w; w.f = f;
    uint32_t r = w.i + 0x7fffu + ((w.i >> 16) & 1u);
    return (u16)(r >> 16);
}
// pack two f32 -> two bf16 (RTNE) in one VGPR: lo = a, hi = b
__device__ __forceinline__ uint32_t cvtpk_bf16(float a, float b) {
    uint32_t r;
    asm("v_cvt_pk_bf16_f32 %0, %1, %2" : "=v"(r) : "v"(a), "v"(b));
    return r;
}

// ---------------------------------------------------------------------------
// Kernel 1: transpose f32 weights into bf16 wt[192][512] (unchanged).
// ---------------------------------------------------------------------------
__global__ void prep_wt(const float* __restrict__ Wq, const float* __restrict__ Wk,
                        const float* __restrict__ Wv, u16* __restrict__ wt) {
    int row = blockIdx.x;            // 0..191
    int g = row >> 6, j = row & 63;
    const float* W = (g == 0) ? Wq : (g == 1) ? Wk : Wv;
    for (int k = threadIdx.x; k < CIN; k += blockDim.x)
        wt[row * CIN + k] = f2b(W[k * HD + j]);
}

// ---------------------------------------------------------------------------
// Kernel 2: QKV projection (unchanged from R8). 16-row blocks, 32 KB
// swizzled LDS x-panel staged via global_load_lds, 4 waves x 3 nt-tiles,
// x-copy from the panel. Q pre-scaled by 0.125*log2(e).
// ---------------------------------------------------------------------------
__global__ __launch_bounds__(256) void proj(
    const float* __restrict__ x, const u16* __restrict__ wt,
    const float* __restrict__ bq, const float* __restrict__ bk, const float* __restrict__ bv,
    u16* __restrict__ qb, u16* __restrict__ kbuf, u16* __restrict__ vtb,
    float* __restrict__ out)
{
    __shared__ __align__(16) float xs[16 * 512];   // 32 KiB x-panel (swizzled)

    int tid = threadIdx.x;
    int lane = tid & 63, w = tid >> 6;   // 4 waves
    int m = lane & 15, quad = lane >> 4;
    int r0 = blockIdx.x * 16;            // first global row of this block

    {
        int rw = w >> 1;                  // wave-uniform row parity
        int pp = (w & 1) * 64 + lane;     // phys granule within row
#pragma unroll
        for (int k = 0; k < 8; k++) {
            int r = k * 2 + rw;
            int g = pp ^ (r & 15);
            const float* src = x + (size_t)(r0 + r) * CIN + g * 4;
            float* dst = xs + (size_t)(k * 256 + w * 64 + lane) * 4;
            __builtin_amdgcn_global_load_lds(
                (const __attribute__((address_space(1))) void*)src,
                (__attribute__((address_space(3))) void*)dst, 16, 0, 0);
        }
    }
    __syncthreads();   // drains vmcnt -> panel ready

    int ntb = w * 3;                      // this wave's 3 output tiles

    f32x4 acc[3];
#pragma unroll
    for (int i = 0; i < 3; i++) acc[i] = (f32x4){0.f, 0.f, 0.f, 0.f};

    const float* xrow = xs + (size_t)m * 512;   // LDS row (MFMA k-row = m)

#pragma unroll
    for (int c = 0; c < 16; c++) {
        int L0 = c * 8 + quad * 2;           // logical granule of this lane's 8 floats
        f32x4 va = *(const f32x4*)(xrow + (size_t)((L0 ^ m) * 4));
        f32x4 vb = *(const f32x4*)(xrow + (size_t)(((L0 + 1) ^ m) * 4));
        bf16x8 a;
#pragma unroll
        for (int j = 0; j < 4; j++) { a[j] = (short)f2b(va[j]); a[4 + j] = (short)f2b(vb[j]); }
#pragma unroll
        for (int t = 0; t < 3; t++) {
            int nt = ntb + t;
            bf16x8 b = *(const bf16x8*)(wt + (size_t)(nt * 16 + m) * CIN + c * 32 + quad * 8);
            acc[t] = __builtin_amdgcn_mfma_f32_16x16x32_bf16(a, b, acc[t], 0, 0, 0);
        }
    }

#pragma unroll
    for (int k = 0; k < 8; k++) {
        int G = k * 256 + tid;
        int r = G >> 7, p = G & 127;
        f32x4 v = *(const f32x4*)(xs + (size_t)G * 4);
        int col = (p ^ (r & 15)) * 4;
        *(f32x4*)(out + (size_t)(r0 + r) * OC + col) = v;
    }

    int n  = r0 >> 12;          // batch
    int tl = r0 & (SEQ - 1);    // t within batch

    const float SCQ = 0.125f * 1.44269504088896f;   // scale * log2(e), baked into Q

#pragma unroll
    for (int t = 0; t < 3; t++) {
        int nt = ntb + t;                 // 0..11, wave-uniform
        int bi = (nt & 3) * 16 + m;       // column within its 64-wide matrix
        if (nt < 4) {
            float biasq = bq[bi];
#pragma unroll
            for (int reg = 0; reg < 4; reg++) {
                size_t r = (size_t)(r0 + quad * 4 + reg);
                qb[r * HD + bi] = f2b((acc[t][reg] + biasq) * SCQ);
            }
        } else if (nt < 8) {
            float biask = bk[bi];
#pragma unroll
            for (int reg = 0; reg < 4; reg++) {
                size_t r = (size_t)(r0 + quad * 4 + reg);
                kbuf[r * HD + bi] = f2b(acc[t][reg] + biask);
            }
        } else {
            float biasv = bv[bi];
            u16x4 pk;
#pragma unroll
            for (int reg = 0; reg < 4; reg++) pk[reg] = f2b(acc[t][reg] + biasv);
            u16* vp = vtb + (size_t)(n * HD + bi) * SEQ + tl + quad * 4;
            *(u16x4*)vp = pk;
        }
    }
}

// ---------------------------------------------------------------------------
// Kernel 3: causal flash attention, R9: COOPERATIVE LDS STAGING, QBLK=64.
// Diagnosis: every non-crippled structure since R1 saturates ~6-8 TB/s of
// shared-cache BW on per-wave K/V loads (R6: 266 MB / 43 us = 6.2 TB/s;
// R1: 7.7; R8 doubled softmax VALU and regressed). Fix the BYTES:
//  - 256 blocks (4 batches x 64 q-tiles of 64 queries), 512 thr = 8 waves
//    = 4 q-subtiles x 2 key-parities. NO work duplication.
//  - Per super-iteration the block stages TWO K/V tiles (kb = 2si, 2si+1;
//    32 KB) into LDS via global_load_lds with PRE-SWIZZLED global source
//    (phys granule p of row r holds logical granule p ^ (r&7)) -> the
//    128-B rows read at the conflict-free b128 floor. Every staged byte
//    serves 64 queries: traffic 266 -> 133 MB, fetched once per block.
//  - Stage-ahead double buffer: issue next stage at iteration top, compute
//    current from LDS (ds_read ~12cy vs 200-400cy L2), __syncthreads at
//    iteration end drains a stage that has had the whole compute to land.
//  - End: 2-way kr-merge + LDS transpose in the dead stage buffer ->
//    coalesced f32x4 stores.
// Numerics: Q pre-scaled, l via ones-MFMA, defer-max THR=8, cvt_pk pack.
// LDS: 64 KB stage + 18.4 KB P = 82.4 KB -> 1 block/CU, 8 waves.
// ---------------------------------------------------------------------------
__global__ __launch_bounds__(512) void attn(
    const u16* __restrict__ qb, const u16* __restrict__ kbuf,
    const u16* __restrict__ vtb, float* __restrict__ out)
{
    __shared__ __align__(16) u16 kv[2][2][2][64 * 64];  // [buf][tilepar][K/V] 64 KiB
    __shared__ __align__(16) short plds[8][16 * 72];    // per-wave P^T (18.4 KiB)

    int tid = threadIdx.x;
    int lane = tid & 63, w = tid >> 6;   // 8 waves
    int m = lane & 15, quad = lane >> 4;
    int qs = w >> 1, kr = w & 1;         // wave = (q-subtile, key-parity)

    int idx = blockIdx.x;                 // 0..255
    int xcd = idx & 7;                    // blockIdx round-robins across XCDs
    int batch = xcd >> 1;                 // 2 XCDs per batch (K/V L2-resident)
    int li = idx >> 3;                    // 0..31
    int jj = 63 - (li * 2 + (xcd & 1));   // q-tile 0..63 (both XCDs of a batch cover all)
    int t0q = jj * 64;                    // first query of this block
    int nkb = jj + 1;                     // 64-key blocks needed
    int S = (nkb + 1) >> 1;               // super-iterations (2 kb each)

    // staging descriptors: thread tid -> granule (row sr, phys slot sp)
    int sr = tid >> 3;                    // row 0..63 (key for K, vdim for V)
    int sp = tid & 7;                     // phys 16B-granule within 128B row
    int sg = sp ^ (sr & 7);               // logical granule staged here
    const u16* ksrc = kbuf + ((size_t)(batch << 12) + sr) * 64 + sg * 8;  // + kb*4096
    const u16* vsrc = vtb + (((size_t)(batch * 64 + sr)) << 12) + sg * 8; // + kb*64

    auto STAGE = [&](int buf, int si) {
        int kb0 = 2 * si;
        __builtin_amdgcn_global_load_lds(
            (const __attribute__((address_space(1))) void*)(ksrc + (size_t)kb0 * 4096),
            (__attribute__((address_space(3))) void*)(&kv[buf][0][0][0] + tid * 8), 16, 0, 0);
        __builtin_amdgcn_global_load_lds(
            (const __attribute__((address_space(1))) void*)(vsrc + (size_t)kb0 * 64),
            (__attribute__((address_space(3))) void*)(&kv[buf][0][1][0] + tid * 8), 16, 0, 0);
        if (kb0 + 1 < nkb) {
            __builtin_amdgcn_global_load_lds(
                (const __attribute__((address_space(1))) void*)(ksrc + (size_t)(kb0 + 1) * 4096),
                (__attribute__((address_space(3))) void*)(&kv[buf][1][0][0] + tid * 8), 16, 0, 0);
            __builtin_amdgcn_global_load_lds(
                (const __attribute__((address_space(1))) void*)(vsrc + (size_t)(kb0 + 1) * 64),
                (__attribute__((address_space(3))) void*)(&kv[buf][1][1][0] + tid * 8), 16, 0, 0);
        }
    };

    bf16x8 ones;
#pragma unroll
    for (int i = 0; i < 8; i++) ones[i] = (short)0x3F80;   // bf16 1.0

    // Q B-frags for this wave's 16 queries (pre-scaled in proj)
    const u16* qp = qb + ((size_t)(batch << 12) + t0q + qs * 16 + m) * 64 + quad * 8;
    bf16x8 qf0 = *(const bf16x8*)qp;
    bf16x8 qf1 = *(const bf16x8*)(qp + 32);

    float mst = -1e30f;
    f32x4 o[4], ol;
#pragma unroll
    for (int nt = 0; nt < 4; nt++) o[nt] = (f32x4){0.f, 0.f, 0.f, 0.f};
    ol = (f32x4){0.f, 0.f, 0.f, 0.f};

    short* pw = &plds[w][0];
    int px = m & 7;                       // swizzle key for this lane's rows

    STAGE(0, 0);
    __syncthreads();

    int buf = 0;
    for (int si = 0; si < S; si++) {
        if (si + 1 < S) STAGE(buf ^ 1, si + 1);   // async, lands during compute

        int kb = 2 * si + kr;
        if (kb < nkb) {                   // wave-uniform
            const u16* Kl = &kv[buf][kr][0][0];
            const u16* Vl = &kv[buf][kr][1][0];

            // S^T = K Q^T from LDS (swizzled rows)
            f32x4 s[4];
#pragma unroll
            for (int st = 0; st < 4; st++) {
                int r = st * 16 + m;
                bf16x8 k0 = *(const bf16x8*)(Kl + (size_t)(r * 8 + (quad ^ px)) * 8);
                bf16x8 k1 = *(const bf16x8*)(Kl + (size_t)(r * 8 + ((quad + 4) ^ px)) * 8);
                f32x4 a = (f32x4){0.f, 0.f, 0.f, 0.f};
                a = __builtin_amdgcn_mfma_f32_16x16x32_bf16(k0, qf0, a, 0, 0, 0);
                a = __builtin_amdgcn_mfma_f32_16x16x32_bf16(k1, qf1, a, 0, 0, 0);
                s[st] = a;
            }

            // causal mask only on the diagonal block
            if (kb == nkb - 1) {
#pragma unroll
                for (int st = 0; st < 4; st++)
#pragma unroll
                    for (int r = 0; r < 4; r++) {
                        int key = kb * 64 + st * 16 + quad * 4 + r;
                        if (key > t0q + qs * 16 + m) s[st][r] = -1e30f;
                    }
            }

            // online softmax (per-query state; query = m)
            float mx = -1e30f;
#pragma unroll
            for (int st = 0; st < 4; st++) {
                float a01 = fmaxf(s[st][0], s[st][1]);
                float a23 = fmaxf(s[st][2], s[st][3]);
                mx = fmaxf(mx, fmaxf(a01, a23));
            }
            mx = fmaxf(mx, __shfl_xor(mx, 16, 64));
            mx = fmaxf(mx, __shfl_xor(mx, 32, 64));

            if (__any(mx > mst + 8.0f)) {     // defer-max
                float mn = fmaxf(mst, mx);
                float al = exp2f(mst - mn);
#pragma unroll
                for (int nt = 0; nt < 4; nt++)
#pragma unroll
                    for (int r = 0; r < 4; r++) o[nt][r] *= al;
                ol[0] *= al;
                mst = mn;
            }

            // P = 2^(s - m), pack bf16 P^T into this wave's LDS buffer
#pragma unroll
            for (int st = 0; st < 4; st++) {
                float e0 = exp2f(s[st][0] - mst);
                float e1 = exp2f(s[st][1] - mst);
                float e2 = exp2f(s[st][2] - mst);
                float e3 = exp2f(s[st][3] - mst);
                uint2 pk2;
                pk2.x = cvtpk_bf16(e0, e1);
                pk2.y = cvtpk_bf16(e2, e3);
                *(uint2*)(pw + m * 72 + st * 16 + quad * 4) = pk2;
            }
            __asm__ volatile("" ::: "memory");
            bf16x8 pf0 = *(const bf16x8*)(pw + m * 72 + quad * 8);
            bf16x8 pf1 = *(const bf16x8*)(pw + m * 72 + 32 + quad * 8);
            __asm__ volatile("" ::: "memory");

            // O^T += V^T P^T (V from LDS); l += ones . P^T
#pragma unroll
            for (int nt = 0; nt < 4; nt++) {
                int r = nt * 16 + m;
                bf16x8 v0 = *(const bf16x8*)(Vl + (size_t)(r * 8 + (quad ^ px)) * 8);
                bf16x8 v1 = *(const bf16x8*)(Vl + (size_t)(r * 8 + ((quad + 4) ^ px)) * 8);
                o[nt] = __builtin_amdgcn_mfma_f32_16x16x32_bf16(v0, pf0, o[nt], 0, 0, 0);
                o[nt] = __builtin_amdgcn_mfma_f32_16x16x32_bf16(v1, pf1, o[nt], 0, 0, 0);
            }
            ol = __builtin_amdgcn_mfma_f32_16x16x32_bf16(ones, pf0, ol, 0, 0, 0);
            ol = __builtin_amdgcn_mfma_f32_16x16x32_bf16(ones, pf1, ol, 0, 0, 0);
        }

        __syncthreads();    // stage drained (overlapped with compute) + dbuf swap
        buf ^= 1;
    }

    // ---- 2-way kr merge + transpose, reusing the dead stage buffer ----
    float* mg = (float*)&kv[0][0][0][0];       // partials: 4 qs x 1120 f32
    float* tb = mg + 8192;                     // transpose: 4 qs x 1088 f32

    if (kr == 1) {
        float* b = mg + qs * 1120;
#pragma unroll
        for (int nt = 0; nt < 4; nt++)
            *(f32x4*)&b[m * 68 + nt * 16 + quad * 4] = o[nt];
        if (quad == 0) { b[1088 + m] = mst; b[1104 + m] = ol[0]; }
    }
    __syncthreads();

    if (kr == 0) {
        float* b = mg + qs * 1120;
        float m1 = b[1088 + m], l1 = b[1104 + m];
        float M = fmaxf(mst, m1);
        float c0 = exp2f(mst - M), c1 = exp2f(m1 - M);
        float L = ol[0] * c0 + l1 * c1;
        float inv = 1.0f / L;
        float* t = tb + qs * 1088;             // [64 v][17] padded
#pragma unroll
        for (int nt = 0; nt < 4; nt++) {
            f32x4 o1 = *(const f32x4*)&b[m * 68 + nt * 16 + quad * 4];
#pragma unroll
            for (int r = 0; r < 4; r++) {
                float val = (o[nt][r] * c0 + o1[r] * c1) * inv;
                t[(nt * 16 + quad * 4 + r) * 17 + m] = val;
            }
        }
        __asm__ volatile("" ::: "memory");
        int q = lane >> 2, vg = lane & 3;      // q 0..15, v-group 0..3 (16 each)
        float* op = out + (size_t)(batch * SEQ + t0q + qs * 16 + q) * OC + CIN + vg * 16;
#pragma unroll
        for (int a = 0; a < 4; a++) {
            f32x4 rv;
#pragma unroll
            for (int i = 0; i < 4; i++) rv[i] = t[(vg * 16 + a * 4 + i) * 17 + q];
            *(f32x4*)(op + a * 4) = rv;
        }
    }
}

// ---------------------------------------------------------------------------
extern "C" void kernel_launch(void* const* d_in, const int* in_sizes, int n_in,
                              void* d_out, int out_size, void* d_ws, size_t ws_size,
                              hipStream_t stream) {
    const float* x  = (const float*)d_in[0];
    const float* Wq = (const float*)d_in[1];
    const float* bq = (const float*)d_in[2];
    const float* Wk = (const float*)d_in[3];
    const float* bk = (const float*)d_in[4];
    const float* Wv = (const float*)d_in[5];
    const float* bv = (const float*)d_in[6];
    float* out = (float*)d_out;

    u16* ws  = (u16*)d_ws;
    u16* wt  = ws;                          // 192*512 elems (pad to 128K)
    u16* qb  = ws + 131072;                 // 16384*64 = 1M elems
    u16* kb  = qb + 16384 * 64;
    u16* vtb = kb + 16384 * 64;             // transposed v: [4][64][4096]

    prep_wt<<<dim3(192), dim3(256), 0, stream>>>(Wq, Wk, Wv, wt);
    proj<<<dim3(1024), dim3(256), 0, stream>>>(x, wt, bq, bk, bv, qb, kb, vtb, out);
    attn<<<dim3(256), dim3(512), 0, stream>>>(qb, kb, vtb, out);
}

// Round 10
// 140.584 us; speedup vs baseline: 1.4583x; 1.1831x over previous
//
#include <hip/hip_runtime.h>
#include <stdint.h>

typedef __attribute__((ext_vector_type(8))) short bf16x8;
typedef __attribute__((ext_vector_type(4))) float f32x4;
typedef __attribute__((ext_vector_type(4))) unsigned short u16x4;
typedef unsigned short u16;

#define NBATCH 4
#define SEQ    4096
#define CIN    512
#define HD     64
#define OC     576      // f32 elements per out row
#define NROW   (NBATCH * SEQ)
#define KVB    262144   // u16 elements per batch in K / V tiled buffers

__device__ __forceinline__ float b2f(u16 u) {
    union { uint32_t i; float f; } w; w.i = ((uint32_t)u) << 16; return w.f;
}
__device__ __forceinline__ u16 f2b(float f) {
    union { float f; uint32_t i; } w; w.f = f;
    uint32_t r = w.i + 0x7fffu + ((w.i >> 16) & 1u);
    return (u16)(r >> 16);
}
// pack two f32 -> two bf16 (RTNE) in one VGPR: lo = a, hi = b
__device__ __forceinline__ uint32_t cvtpk_bf16(float a, float b) {
    uint32_t r;
    asm("v_cvt_pk_bf16_f32 %0, %1, %2" : "=v"(r) : "v"(a), "v"(b));
    return r;
}

// ---------------------------------------------------------------------------
// Kernel 1: transpose f32 weights into bf16 wt[192][512] (unchanged).
// ---------------------------------------------------------------------------
__global__ void prep_wt(const float* __restrict__ Wq, const float* __restrict__ Wk,
                        const float* __restrict__ Wv, u16* __restrict__ wt) {
    int row = blockIdx.x;            // 0..191
    int g = row >> 6, j = row & 63;
    const float* W = (g == 0) ? Wq : (g == 1) ? Wk : Wv;
    for (int k = threadIdx.x; k < CIN; k += blockDim.x)
        wt[row * CIN + k] = f2b(W[k * HD + j]);
}

// ---------------------------------------------------------------------------
// Kernel 2: QKV projection (R9 structure; R10 change = K/V stores target
// FRAGMENT-MAJOR tiled layouts so attn's frag loads are dense 1KB txns):
//   K: [batch][key/16][c/8][key%16][8]   (2KB per 16-key tile)
//   V: [batch][v/16][key/32][(key/8)%4][v%16][8]
// 16-row blocks, 32 KB swizzled LDS x-panel staged via global_load_lds,
// 4 waves x 3 nt-tiles, x-copy from the panel. Q pre-scaled by
// 0.125*log2(e). (V stores coalesce BETTER than the old [v][SEQ] layout.)
// ---------------------------------------------------------------------------
__global__ __launch_bounds__(256) void proj(
    const float* __restrict__ x, const u16* __restrict__ wt,
    const float* __restrict__ bq, const float* __restrict__ bk, const float* __restrict__ bv,
    u16* __restrict__ qb, u16* __restrict__ kbuf, u16* __restrict__ vtb,
    float* __restrict__ out)
{
    __shared__ __align__(16) float xs[16 * 512];   // 32 KiB x-panel (swizzled)

    int tid = threadIdx.x;
    int lane = tid & 63, w = tid >> 6;   // 4 waves
    int m = lane & 15, quad = lane >> 4;
    int r0 = blockIdx.x * 16;            // first global row of this block

    {
        int rw = w >> 1;                  // wave-uniform row parity
        int pp = (w & 1) * 64 + lane;     // phys granule within row
#pragma unroll
        for (int k = 0; k < 8; k++) {
            int r = k * 2 + rw;
            int g = pp ^ (r & 15);
            const float* src = x + (size_t)(r0 + r) * CIN + g * 4;
            float* dst = xs + (size_t)(k * 256 + w * 64 + lane) * 4;
            __builtin_amdgcn_global_load_lds(
                (const __attribute__((address_space(1))) void*)src,
                (__attribute__((address_space(3))) void*)dst, 16, 0, 0);
        }
    }
    __syncthreads();   // drains vmcnt -> panel ready

    int ntb = w * 3;                      // this wave's 3 output tiles

    f32x4 acc[3];
#pragma unroll
    for (int i = 0; i < 3; i++) acc[i] = (f32x4){0.f, 0.f, 0.f, 0.f};

    const float* xrow = xs + (size_t)m * 512;   // LDS row (MFMA k-row = m)

#pragma unroll
    for (int c = 0; c < 16; c++) {
        int L0 = c * 8 + quad * 2;           // logical granule of this lane's 8 floats
        f32x4 va = *(const f32x4*)(xrow + (size_t)((L0 ^ m) * 4));
        f32x4 vb = *(const f32x4*)(xrow + (size_t)(((L0 + 1) ^ m) * 4));
        bf16x8 a;
#pragma unroll
        for (int j = 0; j < 4; j++) { a[j] = (short)f2b(va[j]); a[4 + j] = (short)f2b(vb[j]); }
#pragma unroll
        for (int t = 0; t < 3; t++) {
            int nt = ntb + t;
            bf16x8 b = *(const bf16x8*)(wt + (size_t)(nt * 16 + m) * CIN + c * 32 + quad * 8);
            acc[t] = __builtin_amdgcn_mfma_f32_16x16x32_bf16(a, b, acc[t], 0, 0, 0);
        }
    }

#pragma unroll
    for (int k = 0; k < 8; k++) {
        int G = k * 256 + tid;
        int r = G >> 7, p = G & 127;
        f32x4 v = *(const f32x4*)(xs + (size_t)G * 4);
        int col = (p ^ (r & 15)) * 4;
        *(f32x4*)(out + (size_t)(r0 + r) * OC + col) = v;
    }

    int n  = r0 >> 12;          // batch
    int tl = r0 & (SEQ - 1);    // t within batch (16-aligned)

    const float SCQ = 0.125f * 1.44269504088896f;   // scale * log2(e), baked into Q

#pragma unroll
    for (int t = 0; t < 3; t++) {
        int nt = ntb + t;                 // 0..11, wave-uniform
        int bi = (nt & 3) * 16 + m;       // column within its 64-wide matrix
        if (nt < 4) {
            float biasq = bq[bi];
#pragma unroll
            for (int reg = 0; reg < 4; reg++) {
                size_t r = (size_t)(r0 + quad * 4 + reg);
                qb[r * HD + bi] = f2b((acc[t][reg] + biasq) * SCQ);
            }
        } else if (nt < 8) {
            // K tiled store: [n][tl/16][bi>>3][key%16][bi&7]
            float biask = bk[bi];
            u16* kbase = kbuf + (size_t)n * KVB
                       + (((size_t)(tl >> 4) * 8 + (bi >> 3)) * 16) * 8 + (bi & 7);
#pragma unroll
            for (int reg = 0; reg < 4; reg++) {
                int mkey = quad * 4 + reg;
                kbase[(size_t)mkey * 8] = f2b(acc[t][reg] + biask);
            }
        } else {
            // V tiled store: [n][bi>>4][key/32][(key>>3)&3][bi&15][key&7]
            float biasv = bv[bi];
            u16x4 pk;
#pragma unroll
            for (int reg = 0; reg < 4; reg++) pk[reg] = f2b(acc[t][reg] + biasv);
            int key0 = tl + quad * 4;
            size_t off = ((((size_t)(bi >> 4) * 128 + (key0 >> 5)) * 4
                           + ((key0 >> 3) & 3)) * 16 + (bi & 15)) * 8 + (key0 & 7);
            *(u16x4*)(vtb + (size_t)n * KVB + off) = pk;
        }
    }
}

// ---------------------------------------------------------------------------
// Kernel 3: causal flash attention. R10 = R6's best-measured structure
// VERBATIM (grid 512, 8 waves, LPT heavy-first, XCD-batch affinity, union
// LDS P/merge, 2 q-chains, Q pre-scaled, l via ones-MFMA, defer-max THR=8,
// cvt_pk packing, launch_bounds (512,2)) with ONE change: K/V frag loads
// read the new FRAGMENT-MAJOR layouts -> each load inst is a dense 1KB
// contiguous transaction (8 full 128B lines, every byte used) instead of
// 16 scattered half-lines. Theory: the structure-invariant ~3200cy/unit
// across R0-R6 is memory-pipe occupancy + 2x line over-fetch from the
// scattered frag loads (256 line-requests/unit -> 32).
// ---------------------------------------------------------------------------
__global__ __launch_bounds__(512, 2) void attn(
    const u16* __restrict__ qb, const u16* __restrict__ kbuf,
    const u16* __restrict__ vtb, float* __restrict__ out)
{
    __shared__ __align__(16) union {
        short p[8][16 * 72];     // P^T per wave (18.4 KiB) - visit phase
        float o[8][16][68];      // O^T partials (34.8 KiB) - merge phase
    } lu;
    __shared__ float ldsm[8][16];                        // m partials [w][t]
    __shared__ float ldsl[8][16];                        // l partials [w][t]

    int tid = threadIdx.x;
    int lane = tid & 63, w = tid >> 6;   // 8 waves
    int m = lane & 15, quad = lane >> 4;

    int idx = blockIdx.x;                 // 0..511
    int xcd = idx & 7;                    // HW round-robins blockIdx across XCDs
    int batch = xcd >> 1;                 // 2 XCDs per batch
    int sub = (idx >> 3) * 2 + (xcd & 1); // 0..127
    int jj = 127 - sub;                   // LPT: heavy tile first
    int t0 = jj * 32;
    int nkb = (jj >> 1) + 1;              // 64-key blocks needed
    int lastkb = nkb - 1;

    const u16* kpb = kbuf + (size_t)batch * KVB;   // tiled K base
    const u16* vpb = vtb + (size_t)batch * KVB;    // tiled V base

    bf16x8 ones;
#pragma unroll
    for (int i = 0; i < 8; i++) ones[i] = (short)0x3F80;   // bf16 1.0

    const u16* qpb = qb + (size_t)(batch * SEQ + t0 + m) * HD + quad * 8;
    bf16x8 q0[2], q1[2];
#pragma unroll
    for (int q = 0; q < 2; q++) {
        q0[q] = *(const bf16x8*)(qpb + (size_t)(q * 16) * HD);
        q1[q] = *(const bf16x8*)(qpb + (size_t)(q * 16) * HD + 32);
    }

    float mst[2];
    f32x4 o[2][4], ol[2];
#pragma unroll
    for (int q = 0; q < 2; q++) {
        mst[q] = -1e30f;
        ol[q] = (f32x4){0.f, 0.f, 0.f, 0.f};
#pragma unroll
        for (int nt = 0; nt < 4; nt++) o[q][nt] = (f32x4){0.f, 0.f, 0.f, 0.f};
    }

    int cnt = (nkb > w) ? ((nkb - w + 7) >> 3) : 0;
    int kb = w;
    short* pw = &lu.p[w][0];

    // preload K A-frags for first kb (in-bounds even when cnt==0: kb<=7)
    // K frag: tile = kb*4+st; k0 at g8=quad, k1 at g8=quad+4 -> dense 1KB
    bf16x8 k0[4], k1[4];
#pragma unroll
    for (int st = 0; st < 4; st++) {
        k0[st] = *(const bf16x8*)(kpb + (size_t)((kb * 4 + st) * 8 + quad) * 128 + m * 8);
        k1[st] = *(const bf16x8*)(kpb + (size_t)((kb * 4 + st) * 8 + quad + 4) * 128 + m * 8);
    }

    for (int it = 0; it < cnt; it++, kb += 8) {
        int s0 = kb * 64;
        bool diag = (kb == lastkb);

        // V loads (dense 1KB frag txns), issued early, consumed after softmax
        bf16x8 vf0[4], vf1[4];
#pragma unroll
        for (int nt = 0; nt < 4; nt++) {
            vf0[nt] = *(const bf16x8*)(vpb + (size_t)((nt * 128 + (s0 >> 5)) * 4 + quad) * 128 + m * 8);
            vf1[nt] = *(const bf16x8*)(vpb + (size_t)((nt * 128 + (s0 >> 5) + 1) * 4 + quad) * 128 + m * 8);
        }

        // S^T = K Q^T for both q sub-tiles (scores pre-scaled via Q)
        f32x4 s[2][4];
#pragma unroll
        for (int q = 0; q < 2; q++)
#pragma unroll
            for (int st = 0; st < 4; st++) {
                f32x4 a = (f32x4){0.f, 0.f, 0.f, 0.f};
                a = __builtin_amdgcn_mfma_f32_16x16x32_bf16(k0[st], q0[q], a, 0, 0, 0);
                a = __builtin_amdgcn_mfma_f32_16x16x32_bf16(k1[st], q1[q], a, 0, 0, 0);
                s[q][st] = a;
            }

        // last K use done: prefetch next key-block for this wave
        if (it + 1 < cnt) {
            int kn = kb + 8;
#pragma unroll
            for (int st = 0; st < 4; st++) {
                k0[st] = *(const bf16x8*)(kpb + (size_t)((kn * 4 + st) * 8 + quad) * 128 + m * 8);
                k1[st] = *(const bf16x8*)(kpb + (size_t)((kn * 4 + st) * 8 + quad + 4) * 128 + m * 8);
            }
        }

        // causal mask only on the diagonal block (wave-uniform branch)
        if (diag) {
#pragma unroll
            for (int q = 0; q < 2; q++)
#pragma unroll
                for (int st = 0; st < 4; st++)
#pragma unroll
                    for (int r = 0; r < 4; r++) {
                        int key = s0 + st * 16 + quad * 4 + r;
                        if (key > t0 + q * 16 + m) s[q][st][r] = -1e30f;
                    }
        }

        // softmax + P^T pack + PV, q-chains share one P buffer (per wave)
        bf16x8 pf0[2], pf1[2];
#pragma unroll
        for (int q = 0; q < 2; q++) {
            float mx = -1e30f;
#pragma unroll
            for (int st = 0; st < 4; st++) {
                float a01 = fmaxf(s[q][st][0], s[q][st][1]);
                float a23 = fmaxf(s[q][st][2], s[q][st][3]);
                mx = fmaxf(mx, fmaxf(a01, a23));
            }
            mx = fmaxf(mx, __shfl_xor(mx, 16, 64));
            mx = fmaxf(mx, __shfl_xor(mx, 32, 64));

            // defer-max: only rescale when max grew past threshold
            if (__any(mx > mst[q] + 8.0f)) {
                float mn = fmaxf(mst[q], mx);
                float al = exp2f(mst[q] - mn);
#pragma unroll
                for (int nt = 0; nt < 4; nt++)
#pragma unroll
                    for (int r = 0; r < 4; r++) o[q][nt][r] *= al;
                ol[q][0] *= al;   // only reg 0 of ol is ever read
                mst[q] = mn;
            }

#pragma unroll
            for (int st = 0; st < 4; st++) {
                float e0 = exp2f(s[q][st][0] - mst[q]);
                float e1 = exp2f(s[q][st][1] - mst[q]);
                float e2 = exp2f(s[q][st][2] - mst[q]);
                float e3 = exp2f(s[q][st][3] - mst[q]);
                uint2 pk2;
                pk2.x = cvtpk_bf16(e0, e1);
                pk2.y = cvtpk_bf16(e2, e3);
                *(uint2*)(pw + m * 72 + st * 16 + quad * 4) = pk2;
            }
            __asm__ volatile("" ::: "memory");   // pack-writes before frag-reads
            pf0[q] = *(const bf16x8*)(pw + m * 72 + quad * 8);
            pf1[q] = *(const bf16x8*)(pw + m * 72 + 32 + quad * 8);
            __asm__ volatile("" ::: "memory");   // frag-reads before next pack
        }

#pragma unroll
        for (int q = 0; q < 2; q++) {
            // O^T += V^T P^T ; l += ones . P^T (replaces VALU sum-reduce)
#pragma unroll
            for (int nt = 0; nt < 4; nt++) {
                o[q][nt] = __builtin_amdgcn_mfma_f32_16x16x32_bf16(vf0[nt], pf0[q], o[q][nt], 0, 0, 0);
                o[q][nt] = __builtin_amdgcn_mfma_f32_16x16x32_bf16(vf1[nt], pf1[q], o[q][nt], 0, 0, 0);
            }
            ol[q] = __builtin_amdgcn_mfma_f32_16x16x32_bf16(ones, pf0[q], ol[q], 0, 0, 0);
            ol[q] = __builtin_amdgcn_mfma_f32_16x16x32_bf16(ones, pf1[q], ol[q], 0, 0, 0);
        }
    }

    // all waves done with lu.p before lu.o is written (union safety)
    __syncthreads();

    // merge 8 wave-partials per q sub-tile (waves with cnt==0 publish
    // m=-1e30, l=0, O=0 -> zero weight; wave 0 always has work)
#pragma unroll
    for (int q = 0; q < 2; q++) {
        if (quad == 0) { ldsm[w][m] = mst[q]; ldsl[w][m] = ol[q][0]; }
#pragma unroll
        for (int nt = 0; nt < 4; nt++)
            *(f32x4*)&lu.o[w][m][nt * 16 + quad * 4] = o[q][nt];
        __syncthreads();

        if (tid < 256) {
            int t = tid >> 4, vg = tid & 15;
            float mmax = -1e30f;
#pragma unroll
            for (int u = 0; u < 8; u++) mmax = fmaxf(mmax, ldsm[u][t]);
            float L = 0.f;
            f32x4 acc = (f32x4){0.f, 0.f, 0.f, 0.f};
#pragma unroll
            for (int u = 0; u < 8; u++) {
                float c = exp2f(ldsm[u][t] - mmax);
                L += ldsl[u][t] * c;
                f32x4 ov = *(const f32x4*)&lu.o[u][t][vg * 4];
#pragma unroll
                for (int i2 = 0; i2 < 4; i2++) acc[i2] += ov[i2] * c;
            }
            float inv = 1.0f / L;
            f32x4 res;
#pragma unroll
            for (int i2 = 0; i2 < 4; i2++) res[i2] = acc[i2] * inv;
            *(f32x4*)(out + (size_t)(batch * SEQ + t0 + q * 16 + t) * OC + CIN + vg * 4) = res;
        }
        __syncthreads();   // lu.o reused by next q
    }
}

// ---------------------------------------------------------------------------
extern "C" void kernel_launch(void* const* d_in, const int* in_sizes, int n_in,
                              void* d_out, int out_size, void* d_ws, size_t ws_size,
                              hipStream_t stream) {
    const float* x  = (const float*)d_in[0];
    const float* Wq = (const float*)d_in[1];
    const float* bq = (const float*)d_in[2];
    const float* Wk = (const float*)d_in[3];
    const float* bk = (const float*)d_in[4];
    const float* Wv = (const float*)d_in[5];
    const float* bv = (const float*)d_in[6];
    float* out = (float*)d_out;

    u16* ws  = (u16*)d_ws;
    u16* wt  = ws;                          // 192*512 elems (pad to 128K)
    u16* qb  = ws + 131072;                 // 16384*64 = 1M elems
    u16* kb  = qb + 16384 * 64;             // tiled K: [4][256tiles][8][16][8]
    u16* vtb = kb + 16384 * 64;             // tiled V: [4][4][128][4][16][8]

    prep_wt<<<dim3(192), dim3(256), 0, stream>>>(Wq, Wk, Wv, wt);
    proj<<<dim3(1024), dim3(256), 0, stream>>>(x, wt, bq, bk, bv, qb, kb, vtb, out);
    attn<<<dim3(512), dim3(512), 0, stream>>>(qb, kb, vtb, out);
}

// Round 11
// 129.120 us; speedup vs baseline: 1.5877x; 1.0888x over previous
//
#include <hip/hip_runtime.h>
#include <stdint.h>

typedef __attribute__((ext_vector_type(8))) short bf16x8;
typedef __attribute__((ext_vector_type(4))) float f32x4;
typedef __attribute__((ext_vector_type(4))) unsigned short u16x4;
typedef unsigned short u16;

#define NBATCH 4
#define SEQ    4096
#define CIN    512
#define HD     64
#define OC     576      // f32 elements per out row
#define NROW   (NBATCH * SEQ)
#define KVB    262144   // u16 elements per batch in K / V tiled buffers

__device__ __forceinline__ float b2f(u16 u) {
    union { uint32_t i; float f; } w; w.i = ((uint32_t)u) << 16; return w.f;
}
__device__ __forceinline__ u16 f2b(float f) {
    union { float f; uint32_t i; } w; w.f = f;
    uint32_t r = w.i + 0x7fffu + ((w.i >> 16) & 1u);
    return (u16)(r >> 16);
}
// pack two f32 -> two bf16 (RTNE) in one VGPR: lo = a, hi = b
__device__ __forceinline__ uint32_t cvtpk_bf16(float a, float b) {
    uint32_t r;
    asm("v_cvt_pk_bf16_f32 %0, %1, %2" : "=v"(r) : "v"(a), "v"(b));
    return r;
}

// ---------------------------------------------------------------------------
// Kernel 1: transpose f32 weights into FRAGMENT-MAJOR bf16 tiles:
// wtt[frag = nt*16 + c][lane = quad*16 + m][8], so proj's B-frag load is
// one dense 1KB transaction (R11; was [192][512] row-major -> 16 scattered
// half-lines per load).
// ---------------------------------------------------------------------------
__global__ void prep_wt(const float* __restrict__ Wq, const float* __restrict__ Wk,
                        const float* __restrict__ Wv, u16* __restrict__ wt) {
    int row = blockIdx.x;            // 0..191
    int g = row >> 6, j = row & 63;
    const float* W = (g == 0) ? Wq : (g == 1) ? Wk : Wv;
    int nt = row >> 4, m = row & 15;
    for (int k = threadIdx.x; k < CIN; k += blockDim.x) {
        int c = k >> 5, qd = (k >> 3) & 3, jj = k & 7;
        size_t off = ((size_t)(nt * 16 + c) * 64 + qd * 16 + m) * 8 + jj;
        wt[off] = f2b(W[k * HD + j]);
    }
}

// ---------------------------------------------------------------------------
// Kernel 2: QKV projection. R11: cure proj's scattered-wt disease (same
// mechanism R10 cured in attn). Diagnosis: per-block 5000 cy/c-iter,
// wt frag loads hit 16 scattered 64B half-lines each (lat-serialized;
// wt is L2-resident so BW is not the issue).
// Changes:
//  - wt loads read the new fragment-major layout: dense 1KB per load.
//  - 32-row blocks (64 KB panel, grid 512 = 2 blocks/CU): each wave
//    processes 3 nt x 2 row-tiles, so each wt frag register feeds 2 MFMAs
//    (wt traffic halves) and the c-loop has 2x the MFMA per load.
//  - x->bf16 via v_cvt_pk_bf16_f32 (8 ops/c-iter, was ~48; same RTNE).
// Staging via global_load_lds with pre-swizzled source (R7 scheme,
// g = p ^ (r&15)); x-copy reads the panel. Q pre-scaled by 0.125*log2(e).
// K/V epilogue stores keep R10's attn-tiled layouts.
// ---------------------------------------------------------------------------
__global__ __launch_bounds__(256) void proj(
    const float* __restrict__ x, const u16* __restrict__ wt,
    const float* __restrict__ bq, const float* __restrict__ bk, const float* __restrict__ bv,
    u16* __restrict__ qb, u16* __restrict__ kbuf, u16* __restrict__ vtb,
    float* __restrict__ out)
{
    __shared__ __align__(16) float xs[32 * 512];   // 64 KiB x-panel (swizzled)

    int tid = threadIdx.x;
    int lane = tid & 63, w = tid >> 6;   // 4 waves
    int m = lane & 15, quad = lane >> 4;
    int r0b = blockIdx.x * 32;           // first global row of this block

    // ---- stage x: 16 rounds of global_load_lds (R7 scheme, verified) ----
    {
        int rw = w >> 1;                  // wave-uniform row parity
        int pp = (w & 1) * 64 + lane;     // phys granule within row
#pragma unroll
        for (int k = 0; k < 16; k++) {
            int r = k * 2 + rw;
            int g = pp ^ (r & 15);
            const float* src = x + (size_t)(r0b + r) * CIN + g * 4;
            float* dst = xs + (size_t)(k * 256 + w * 64 + lane) * 4;
            __builtin_amdgcn_global_load_lds(
                (const __attribute__((address_space(1))) void*)src,
                (__attribute__((address_space(3))) void*)dst, 16, 0, 0);
        }
    }
    __syncthreads();   // drains vmcnt -> panel ready

    int ntb = w * 3;                      // this wave's 3 output tiles

    f32x4 acc0[3], acc1[3];               // [nt] for row-tile 0 / 1
#pragma unroll
    for (int i = 0; i < 3; i++) {
        acc0[i] = (f32x4){0.f, 0.f, 0.f, 0.f};
        acc1[i] = (f32x4){0.f, 0.f, 0.f, 0.f};
    }

    const float* xrow0 = xs + (size_t)m * 512;          // tile0 row (r&15 = m)
    const float* xrow1 = xs + (size_t)(16 + m) * 512;   // tile1 row (r&15 = m)

#pragma unroll
    for (int c = 0; c < 16; c++) {
        int L0 = c * 8 + quad * 2;           // logical granule of this lane's 8 floats
        f32x4 va0 = *(const f32x4*)(xrow0 + (size_t)((L0 ^ m) * 4));
        f32x4 vb0 = *(const f32x4*)(xrow0 + (size_t)(((L0 + 1) ^ m) * 4));
        f32x4 va1 = *(const f32x4*)(xrow1 + (size_t)((L0 ^ m) * 4));
        f32x4 vb1 = *(const f32x4*)(xrow1 + (size_t)(((L0 + 1) ^ m) * 4));
        bf16x8 a0, a1;
        {
            uint32_t* p0 = (uint32_t*)&a0;
            p0[0] = cvtpk_bf16(va0[0], va0[1]);
            p0[1] = cvtpk_bf16(va0[2], va0[3]);
            p0[2] = cvtpk_bf16(vb0[0], vb0[1]);
            p0[3] = cvtpk_bf16(vb0[2], vb0[3]);
            uint32_t* p1 = (uint32_t*)&a1;
            p1[0] = cvtpk_bf16(va1[0], va1[1]);
            p1[1] = cvtpk_bf16(va1[2], va1[3]);
            p1[2] = cvtpk_bf16(vb1[0], vb1[1]);
            p1[3] = cvtpk_bf16(vb1[2], vb1[3]);
        }
#pragma unroll
        for (int t = 0; t < 3; t++) {
            int nt = ntb + t;
            // dense 1KB frag load: wtt[frag = nt*16+c][lane][8]
            bf16x8 b = *(const bf16x8*)(wt + ((size_t)(nt * 16 + c) * 64 + quad * 16 + m) * 8);
            acc0[t] = __builtin_amdgcn_mfma_f32_16x16x32_bf16(a0, b, acc0[t], 0, 0, 0);
            acc1[t] = __builtin_amdgcn_mfma_f32_16x16x32_bf16(a1, b, acc1[t], 0, 0, 0);
        }
    }

    // ---- x-copy from the LDS panel (R7 scheme) ----
#pragma unroll
    for (int k = 0; k < 16; k++) {
        int G = k * 256 + tid;
        int r = G >> 7, p = G & 127;
        f32x4 v = *(const f32x4*)(xs + (size_t)G * 4);
        int col = (p ^ (r & 15)) * 4;
        *(f32x4*)(out + (size_t)(r0b + r) * OC + col) = v;
    }

    const float SCQ = 0.125f * 1.44269504088896f;   // scale * log2(e), baked into Q

#pragma unroll
    for (int tt = 0; tt < 2; tt++) {
        int r0 = r0b + tt * 16;
        int n  = r0 >> 12;          // batch
        int tl = r0 & (SEQ - 1);    // t within batch (16-aligned)
#pragma unroll
        for (int t = 0; t < 3; t++) {
            f32x4 acc = tt ? acc1[t] : acc0[t];
            int nt = ntb + t;                 // 0..11, wave-uniform
            int bi = (nt & 3) * 16 + m;       // column within its 64-wide matrix
            if (nt < 4) {
                float biasq = bq[bi];
#pragma unroll
                for (int reg = 0; reg < 4; reg++) {
                    size_t r = (size_t)(r0 + quad * 4 + reg);
                    qb[r * HD + bi] = f2b((acc[reg] + biasq) * SCQ);
                }
            } else if (nt < 8) {
                // K tiled store: [n][tl/16][bi>>3][key%16][bi&7]
                float biask = bk[bi];
                u16* kbase = kbuf + (size_t)n * KVB
                           + (((size_t)(tl >> 4) * 8 + (bi >> 3)) * 16) * 8 + (bi & 7);
#pragma unroll
                for (int reg = 0; reg < 4; reg++) {
                    int mkey = quad * 4 + reg;
                    kbase[(size_t)mkey * 8] = f2b(acc[reg] + biask);
                }
            } else {
                // V tiled store: [n][bi>>4][key/32][(key>>3)&3][bi&15][key&7]
                float biasv = bv[bi];
                u16x4 pk;
#pragma unroll
                for (int reg = 0; reg < 4; reg++) pk[reg] = f2b(acc[reg] + biasv);
                int key0 = tl + quad * 4;
                size_t off = ((((size_t)(bi >> 4) * 128 + (key0 >> 5)) * 4
                               + ((key0 >> 3) & 3)) * 16 + (bi & 15)) * 8 + (key0 & 7);
                *(u16x4*)(vtb + (size_t)n * KVB + off) = pk;
            }
        }
    }
}

// ---------------------------------------------------------------------------
// Kernel 3: causal flash attention (unchanged from R10, ~31 us).
// R6 structure + fragment-major K/V layouts (dense 1KB frag loads).
// Grid 512, 8 waves, LPT heavy-first, XCD-batch affinity, union LDS,
// 2 q-chains, Q pre-scaled, l via ones-MFMA, defer-max THR=8, cvt_pk.
// ---------------------------------------------------------------------------
__global__ __launch_bounds__(512, 2) void attn(
    const u16* __restrict__ qb, const u16* __restrict__ kbuf,
    const u16* __restrict__ vtb, float* __restrict__ out)
{
    __shared__ __align__(16) union {
        short p[8][16 * 72];     // P^T per wave (18.4 KiB) - visit phase
        float o[8][16][68];      // O^T partials (34.8 KiB) - merge phase
    } lu;
    __shared__ float ldsm[8][16];                        // m partials [w][t]
    __shared__ float ldsl[8][16];                        // l partials [w][t]

    int tid = threadIdx.x;
    int lane = tid & 63, w = tid >> 6;   // 8 waves
    int m = lane & 15, quad = lane >> 4;

    int idx = blockIdx.x;                 // 0..511
    int xcd = idx & 7;                    // HW round-robins blockIdx across XCDs
    int batch = xcd >> 1;                 // 2 XCDs per batch
    int sub = (idx >> 3) * 2 + (xcd & 1); // 0..127
    int jj = 127 - sub;                   // LPT: heavy tile first
    int t0 = jj * 32;
    int nkb = (jj >> 1) + 1;              // 64-key blocks needed
    int lastkb = nkb - 1;

    const u16* kpb = kbuf + (size_t)batch * KVB;   // tiled K base
    const u16* vpb = vtb + (size_t)batch * KVB;    // tiled V base

    bf16x8 ones;
#pragma unroll
    for (int i = 0; i < 8; i++) ones[i] = (short)0x3F80;   // bf16 1.0

    const u16* qpb = qb + (size_t)(batch * SEQ + t0 + m) * HD + quad * 8;
    bf16x8 q0[2], q1[2];
#pragma unroll
    for (int q = 0; q < 2; q++) {
        q0[q] = *(const bf16x8*)(qpb + (size_t)(q * 16) * HD);
        q1[q] = *(const bf16x8*)(qpb + (size_t)(q * 16) * HD + 32);
    }

    float mst[2];
    f32x4 o[2][4], ol[2];
#pragma unroll
    for (int q = 0; q < 2; q++) {
        mst[q] = -1e30f;
        ol[q] = (f32x4){0.f, 0.f, 0.f, 0.f};
#pragma unroll
        for (int nt = 0; nt < 4; nt++) o[q][nt] = (f32x4){0.f, 0.f, 0.f, 0.f};
    }

    int cnt = (nkb > w) ? ((nkb - w + 7) >> 3) : 0;
    int kb = w;
    short* pw = &lu.p[w][0];

    // preload K A-frags for first kb (in-bounds even when cnt==0: kb<=7)
    bf16x8 k0[4], k1[4];
#pragma unroll
    for (int st = 0; st < 4; st++) {
        k0[st] = *(const bf16x8*)(kpb + (size_t)((kb * 4 + st) * 8 + quad) * 128 + m * 8);
        k1[st] = *(const bf16x8*)(kpb + (size_t)((kb * 4 + st) * 8 + quad + 4) * 128 + m * 8);
    }

    for (int it = 0; it < cnt; it++, kb += 8) {
        int s0 = kb * 64;
        bool diag = (kb == lastkb);

        // V loads (dense 1KB frag txns), issued early, consumed after softmax
        bf16x8 vf0[4], vf1[4];
#pragma unroll
        for (int nt = 0; nt < 4; nt++) {
            vf0[nt] = *(const bf16x8*)(vpb + (size_t)((nt * 128 + (s0 >> 5)) * 4 + quad) * 128 + m * 8);
            vf1[nt] = *(const bf16x8*)(vpb + (size_t)((nt * 128 + (s0 >> 5) + 1) * 4 + quad) * 128 + m * 8);
        }

        // S^T = K Q^T for both q sub-tiles (scores pre-scaled via Q)
        f32x4 s[2][4];
#pragma unroll
        for (int q = 0; q < 2; q++)
#pragma unroll
            for (int st = 0; st < 4; st++) {
                f32x4 a = (f32x4){0.f, 0.f, 0.f, 0.f};
                a = __builtin_amdgcn_mfma_f32_16x16x32_bf16(k0[st], q0[q], a, 0, 0, 0);
                a = __builtin_amdgcn_mfma_f32_16x16x32_bf16(k1[st], q1[q], a, 0, 0, 0);
                s[q][st] = a;
            }

        // last K use done: prefetch next key-block for this wave
        if (it + 1 < cnt) {
            int kn = kb + 8;
#pragma unroll
            for (int st = 0; st < 4; st++) {
                k0[st] = *(const bf16x8*)(kpb + (size_t)((kn * 4 + st) * 8 + quad) * 128 + m * 8);
                k1[st] = *(const bf16x8*)(kpb + (size_t)((kn * 4 + st) * 8 + quad + 4) * 128 + m * 8);
            }
        }

        // causal mask only on the diagonal block (wave-uniform branch)
        if (diag) {
#pragma unroll
            for (int q = 0; q < 2; q++)
#pragma unroll
                for (int st = 0; st < 4; st++)
#pragma unroll
                    for (int r = 0; r < 4; r++) {
                        int key = s0 + st * 16 + quad * 4 + r;
                        if (key > t0 + q * 16 + m) s[q][st][r] = -1e30f;
                    }
        }

        // softmax + P^T pack + PV, q-chains share one P buffer (per wave)
        bf16x8 pf0[2], pf1[2];
#pragma unroll
        for (int q = 0; q < 2; q++) {
            float mx = -1e30f;
#pragma unroll
            for (int st = 0; st < 4; st++) {
                float a01 = fmaxf(s[q][st][0], s[q][st][1]);
                float a23 = fmaxf(s[q][st][2], s[q][st][3]);
                mx = fmaxf(mx, fmaxf(a01, a23));
            }
            mx = fmaxf(mx, __shfl_xor(mx, 16, 64));
            mx = fmaxf(mx, __shfl_xor(mx, 32, 64));

            // defer-max: only rescale when max grew past threshold
            if (__any(mx > mst[q] + 8.0f)) {
                float mn = fmaxf(mst[q], mx);
                float al = exp2f(mst[q] - mn);
#pragma unroll
                for (int nt = 0; nt < 4; nt++)
#pragma unroll
                    for (int r = 0; r < 4; r++) o[q][nt][r] *= al;
                ol[q][0] *= al;   // only reg 0 of ol is ever read
                mst[q] = mn;
            }

#pragma unroll
            for (int st = 0; st < 4; st++) {
                float e0 = exp2f(s[q][st][0] - mst[q]);
                float e1 = exp2f(s[q][st][1] - mst[q]);
                float e2 = exp2f(s[q][st][2] - mst[q]);
                float e3 = exp2f(s[q][st][3] - mst[q]);
                uint2 pk2;
                pk2.x = cvtpk_bf16(e0, e1);
                pk2.y = cvtpk_bf16(e2, e3);
                *(uint2*)(pw + m * 72 + st * 16 + quad * 4) = pk2;
            }
            __asm__ volatile("" ::: "memory");   // pack-writes before frag-reads
            pf0[q] = *(const bf16x8*)(pw + m * 72 + quad * 8);
            pf1[q] = *(const bf16x8*)(pw + m * 72 + 32 + quad * 8);
            __asm__ volatile("" ::: "memory");   // frag-reads before next pack
        }

#pragma unroll
        for (int q = 0; q < 2; q++) {
            // O^T += V^T P^T ; l += ones . P^T (replaces VALU sum-reduce)
#pragma unroll
            for (int nt = 0; nt < 4; nt++) {
                o[q][nt] = __builtin_amdgcn_mfma_f32_16x16x32_bf16(vf0[nt], pf0[q], o[q][nt], 0, 0, 0);
                o[q][nt] = __builtin_amdgcn_mfma_f32_16x16x32_bf16(vf1[nt], pf1[q], o[q][nt], 0, 0, 0);
            }
            ol[q] = __builtin_amdgcn_mfma_f32_16x16x32_bf16(ones, pf0[q], ol[q], 0, 0, 0);
            ol[q] = __builtin_amdgcn_mfma_f32_16x16x32_bf16(ones, pf1[q], ol[q], 0, 0, 0);
        }
    }

    // all waves done with lu.p before lu.o is written (union safety)
    __syncthreads();

    // merge 8 wave-partials per q sub-tile (waves with cnt==0 publish
    // m=-1e30, l=0, O=0 -> zero weight; wave 0 always has work)
#pragma unroll
    for (int q = 0; q < 2; q++) {
        if (quad == 0) { ldsm[w][m] = mst[q]; ldsl[w][m] = ol[q][0]; }
#pragma unroll
        for (int nt = 0; nt < 4; nt++)
            *(f32x4*)&lu.o[w][m][nt * 16 + quad * 4] = o[q][nt];
        __syncthreads();

        if (tid < 256) {
            int t = tid >> 4, vg = tid & 15;
            float mmax = -1e30f;
#pragma unroll
            for (int u = 0; u < 8; u++) mmax = fmaxf(mmax, ldsm[u][t]);
            float L = 0.f;
            f32x4 acc = (f32x4){0.f, 0.f, 0.f, 0.f};
#pragma unroll
            for (int u = 0; u < 8; u++) {
                float c = exp2f(ldsm[u][t] - mmax);
                L += ldsl[u][t] * c;
                f32x4 ov = *(const f32x4*)&lu.o[u][t][vg * 4];
#pragma unroll
                for (int i2 = 0; i2 < 4; i2++) acc[i2] += ov[i2] * c;
            }
            float inv = 1.0f / L;
            f32x4 res;
#pragma unroll
            for (int i2 = 0; i2 < 4; i2++) res[i2] = acc[i2] * inv;
            *(f32x4*)(out + (size_t)(batch * SEQ + t0 + q * 16 + t) * OC + CIN + vg * 4) = res;
        }
        __syncthreads();   // lu.o reused by next q
    }
}

// ---------------------------------------------------------------------------
extern "C" void kernel_launch(void* const* d_in, const int* in_sizes, int n_in,
                              void* d_out, int out_size, void* d_ws, size_t ws_size,
                              hipStream_t stream) {
    const float* x  = (const float*)d_in[0];
    const float* Wq = (const float*)d_in[1];
    const float* bq = (const float*)d_in[2];
    const float* Wk = (const float*)d_in[3];
    const float* bk = (const float*)d_in[4];
    const float* Wv = (const float*)d_in[5];
    const float* bv = (const float*)d_in[6];
    float* out = (float*)d_out;

    u16* ws  = (u16*)d_ws;
    u16* wt  = ws;                          // tiled wt: [192 frags][64 lanes][8]
    u16* qb  = ws + 131072;                 // 16384*64 = 1M elems
    u16* kb  = qb + 16384 * 64;             // tiled K: [4][256tiles][8][16][8]
    u16* vtb = kb + 16384 * 64;             // tiled V: [4][4][128][4][16][8]

    prep_wt<<<dim3(192), dim3(256), 0, stream>>>(Wq, Wk, Wv, wt);
    proj<<<dim3(512), dim3(256), 0, stream>>>(x, wt, bq, bk, bv, qb, kb, vtb, out);
    attn<<<dim3(512), dim3(512), 0, stream>>>(qb, kb, vtb, out);
}